// Round 1
// baseline (1096.348 us; speedup 1.0000x reference)
//
#include <hip/hip_runtime.h>
#include <cstdint>
#include <cstddef>

typedef unsigned short u16;
typedef __bf16 bf16x8 __attribute__((ext_vector_type(8)));
typedef float f32x4 __attribute__((ext_vector_type(4)));

typedef const void __attribute__((address_space(1)))* gas_ptr;
typedef void __attribute__((address_space(3)))* las_ptr;

#define TEMP_INV (1.0f / 0.15f)
#define NCH 8
#define CS 512
#define DIM 4096

// RNE float -> bf16
__device__ __forceinline__ u16 f2bf(float f) {
  union { float f; uint32_t u; } a; a.f = f;
  uint32_t r = a.u + 0x7fffu + ((a.u >> 16) & 1u);
  return (u16)(r >> 16);
}

// ---------------------------------------------------------------------------
// Kernel 0: Sinkhorn. Blocks 0..7 = intra chunks (512 thr), block 8 = 8x8
// chunk perm (1 wave). Multiplicative domain: P = diag(u) * E * diag(v),
// E = exp(L/T). Safe without max-subtraction: |L/T| < ~0.5, sums ~512.
// ---------------------------------------------------------------------------
__global__ void sinkhorn_kernel(const float* __restrict__ chunk_logits,
                                const float* __restrict__ intra_logits,
                                float* __restrict__ cp,   // [8][8] fp32
                                float* __restrict__ E,    // [8][512][512] fp32 scratch
                                u16* __restrict__ P)      // [8][512][512] bf16
{
  const int cid = blockIdx.x;
  const int tid = threadIdx.x;

  if (cid == NCH) {            // 8x8 chunk permutation, one wave
    if (tid < 64) {
      float e = expf(chunk_logits[tid] * TEMP_INV);
      float v = 1.0f, u = 0.0f;
      #pragma unroll
      for (int it = 0; it < 5; ++it) {
        float t = e * v;                       // row sums (reduce over j = lane%8)
        t += __shfl_xor(t, 1); t += __shfl_xor(t, 2); t += __shfl_xor(t, 4);
        u = 1.0f / t;
        float t2 = e * u;                      // col sums (reduce over i = lane/8)
        t2 += __shfl_xor(t2, 8); t2 += __shfl_xor(t2, 16); t2 += __shfl_xor(t2, 32);
        v = 1.0f / t2;
      }
      cp[tid] = e * u * v;
    }
    return;
  }

  const float* L = intra_logits + (size_t)cid * CS * CS;
  float* Ec = E + (size_t)cid * CS * CS;
  u16*   Pc = P + (size_t)cid * CS * CS;

  __shared__ float u_s[CS];
  __shared__ float v_s[CS];

  for (int idx = tid; idx < CS * CS; idx += blockDim.x)
    Ec[idx] = expf(L[idx] * TEMP_INV);
  v_s[tid] = 1.0f;
  __syncthreads();

  const int w = tid >> 6, l = tid & 63;
  for (int it = 0; it < 5; ++it) {
    // row pass: wave w handles rows [w*64, w*64+64), coalesced row reads
    for (int rr = 0; rr < 64; ++rr) {
      const int k = (w << 6) + rr;
      const float* row = Ec + (size_t)k * CS;
      float s = 0.0f;
      #pragma unroll
      for (int jj = 0; jj < CS / 64; ++jj) {
        int j = l + jj * 64;
        s += row[j] * v_s[j];
      }
      s += __shfl_xor(s, 1);  s += __shfl_xor(s, 2);  s += __shfl_xor(s, 4);
      s += __shfl_xor(s, 8);  s += __shfl_xor(s, 16); s += __shfl_xor(s, 32);
      if (l == 0) u_s[k] = 1.0f / s;
    }
    __syncthreads();
    // col pass: thread tid owns column j=tid, coalesced across threads
    {
      float s = 0.0f;
      for (int k = 0; k < CS; ++k)
        s += Ec[(size_t)k * CS + tid] * u_s[k];
      v_s[tid] = 1.0f / s;
    }
    __syncthreads();
  }

  for (int idx = tid; idx < CS * CS; idx += blockDim.x) {
    int k = idx >> 9, j = idx & (CS - 1);
    Pc[idx] = f2bf(Ec[idx] * u_s[k] * v_s[j]);
  }
}

// ---------------------------------------------------------------------------
// Kernel 1: stage-1 chunk mixing. ytil[b,i,d] = sum_jc cp[i,jc] * x[b,jc,d].
// Thread handles 4 consecutive d (float4 in, ushort4 bf16 out). Memory-bound.
// ---------------------------------------------------------------------------
__global__ __launch_bounds__(256) void stage1_kernel(
    const float* __restrict__ x,
    const float* __restrict__ cp,
    u16* __restrict__ y)
{
  __shared__ float cps[64];
  const int tid = threadIdx.x;
  if (tid < 64) cps[tid] = cp[tid];
  __syncthreads();

  const int g  = blockIdx.x * 256 + tid;   // over rows*128 float4 slots
  const int b  = g >> 7;
  const int d4 = g & 127;

  const float4* xr = (const float4*)x + (size_t)b * 1024 + d4;
  float4 xi[8];
  #pragma unroll
  for (int jc = 0; jc < 8; ++jc) xi[jc] = xr[(size_t)jc * 128];

  ushort4* yr = (ushort4*)y + (size_t)b * 1024 + d4;
  #pragma unroll
  for (int i = 0; i < 8; ++i) {
    float ax = 0.f, ay = 0.f, az = 0.f, aw = 0.f;
    #pragma unroll
    for (int jc = 0; jc < 8; ++jc) {
      const float wgt = cps[i * 8 + jc];
      ax += wgt * xi[jc].x; ay += wgt * xi[jc].y;
      az += wgt * xi[jc].z; aw += wgt * xi[jc].w;
    }
    ushort4 o;
    o.x = f2bf(ax); o.y = f2bf(ay); o.z = f2bf(az); o.w = f2bf(aw);
    yr[(size_t)i * 128] = o;
  }
}

// ---------------------------------------------------------------------------
// Kernel 2: per-chunk GEMM  out[m, c, n] = sum_k ytil[m, c, k] * P_c[n, k].
// m97 recipe: BM=BN=128, BK=32, 256 thr / 4 waves, each wave 64x64 via 4x4
// frags of 16x16x32 bf16 MFMA, global_load_lds width=16 staging.
// ---------------------------------------------------------------------------
#define BM 128
#define BN 128
#define BK 32

__global__ __launch_bounds__(256) void gemm_kernel(
    const u16* __restrict__ Y,   // [rows][4096] bf16 bits
    const u16* __restrict__ P,   // [8][512][512] bf16 bits
    float* __restrict__ out)     // [rows][4096] fp32
{
  __shared__ u16 As[BM * BK];   // [row][k] row-major, 8 KB
  __shared__ u16 Bs[BN * BK];   // [n][k]  row-major, 8 KB

  const int tid = threadIdx.x;
  const int m0 = blockIdx.x * BM;
  const int n0 = blockIdx.y * BN;
  const int c  = blockIdx.z;

  const u16* Ab = Y + (size_t)m0 * DIM + (size_t)c * CS;
  const u16* Bb = P + (size_t)c * CS * CS + (size_t)n0 * CS;

  const int w = tid >> 6, l = tid & 63;
  const int wm = (w >> 1) * 64, wn = (w & 1) * 64;
  const int lrow = l & 15, lk = (l >> 4) * 8;

  const int colb = (tid & 3) * 8;    // k-subblock for staging loads

  f32x4 acc[4][4] = {};

  for (int k0 = 0; k0 < CS; k0 += BK) {
    // stage A tile: 128 rows x 32 k, 2 rounds x 256 lanes x 16 B
    #pragma unroll
    for (int rd = 0; rd < 2; ++rd) {
      const int idx = rd * 256 + tid;
      const int r = idx >> 2;
      const u16* g = Ab + (size_t)r * DIM + k0 + colb;
      u16* lds = As + ((idx >> 6) << 6) * 8;   // wave-uniform base, lane*16B implicit
      __builtin_amdgcn_global_load_lds((gas_ptr)g, (las_ptr)lds, 16, 0, 0);
    }
    // stage B tile: 128 n-rows x 32 k
    #pragma unroll
    for (int rd = 0; rd < 2; ++rd) {
      const int idx = rd * 256 + tid;
      const int r = idx >> 2;
      const u16* g = Bb + (size_t)r * CS + k0 + colb;
      u16* lds = Bs + ((idx >> 6) << 6) * 8;
      __builtin_amdgcn_global_load_lds((gas_ptr)g, (las_ptr)lds, 16, 0, 0);
    }
    __syncthreads();

    bf16x8 af[4], bfr[4];
    #pragma unroll
    for (int mi = 0; mi < 4; ++mi)
      af[mi] = *(const bf16x8*)&As[(wm + mi * 16 + lrow) * BK + lk];
    #pragma unroll
    for (int ni = 0; ni < 4; ++ni)
      bfr[ni] = *(const bf16x8*)&Bs[(wn + ni * 16 + lrow) * BK + lk];

    #pragma unroll
    for (int mi = 0; mi < 4; ++mi)
      #pragma unroll
      for (int ni = 0; ni < 4; ++ni)
        acc[mi][ni] = __builtin_amdgcn_mfma_f32_16x16x32_bf16(
            af[mi], bfr[ni], acc[mi][ni], 0, 0, 0);
    __syncthreads();
  }

  // epilogue: C/D layout col = lane&15, row = (lane>>4)*4 + r  [m89/m91]
  const int ccol = l & 15, rquad = (l >> 4) * 4;
  #pragma unroll
  for (int mi = 0; mi < 4; ++mi) {
    #pragma unroll
    for (int ni = 0; ni < 4; ++ni) {
      #pragma unroll
      for (int r = 0; r < 4; ++r) {
        const int mm = m0 + wm + mi * 16 + rquad + r;
        const int nn = n0 + wn + ni * 16 + ccol;
        out[(size_t)mm * DIM + (size_t)c * CS + nn] = acc[mi][ni][r];
      }
    }
  }
}

// ---------------------------------------------------------------------------
// ws layout: [0,256) cp fp32 | [4K, 4K+8M) E fp32 | +4M P bf16 | +128M ytil bf16
// total ~140.2 MB
// ---------------------------------------------------------------------------
extern "C" void kernel_launch(void* const* d_in, const int* in_sizes, int n_in,
                              void* d_out, int out_size, void* d_ws, size_t ws_size,
                              hipStream_t stream) {
  const float* x  = (const float*)d_in[0];
  const float* cl = (const float*)d_in[1];
  const float* il = (const float*)d_in[2];
  float* out = (float*)d_out;

  char* ws = (char*)d_ws;
  float* cp = (float*)ws;
  float* E  = (float*)(ws + 4096);
  u16*   P  = (u16*)(ws + 4096 + (size_t)8 * 1024 * 1024);
  u16*   Y  = (u16*)(ws + 4096 + (size_t)12 * 1024 * 1024);

  const int rows = in_sizes[0] / DIM;   // 16384

  sinkhorn_kernel<<<dim3(NCH + 1), dim3(512), 0, stream>>>(cl, il, cp, E, P);
  stage1_kernel<<<dim3(rows / 2), dim3(256), 0, stream>>>(x, cp, Y);
  gemm_kernel<<<dim3(rows / BM, CS / BN, NCH), dim3(256), 0, stream>>>(Y, P, out);
}

// Round 2
// 635.692 us; speedup vs baseline: 1.7247x; 1.7247x over previous
//
#include <hip/hip_runtime.h>
#include <cstdint>
#include <cstddef>

typedef unsigned short u16;
typedef __bf16 bf16x8 __attribute__((ext_vector_type(8)));
typedef float f32x4 __attribute__((ext_vector_type(4)));
typedef u16 u16x8 __attribute__((ext_vector_type(8)));

typedef const void __attribute__((address_space(1)))* gas_ptr;
typedef void __attribute__((address_space(3)))* las_ptr;

#define TEMP_INV (1.0f / 0.15f)
#define NCH 8
#define CS 512
#define DIM 4096
#define NSLAB 16          // k-slabs for column-pass partials (32 rows each)

// RNE float -> bf16
__device__ __forceinline__ u16 f2bf(float f) {
  union { float f; uint32_t u; } a; a.f = f;
  uint32_t r = a.u + 0x7fffu + ((a.u >> 16) & 1u);
  return (u16)(r >> 16);
}

// ---------------------------------------------------------------------------
// RE: E = exp(L/T), first row pass u = 1/rowsum(E) (v==1). One wave per row.
// Block 1024 = the 8x8 chunk-perm sinkhorn (one wave).
// ---------------------------------------------------------------------------
__global__ __launch_bounds__(256) void re_kernel(
    const float* __restrict__ chunk_logits,
    const float* __restrict__ intra_logits,
    float* __restrict__ cp,      // [8][8]
    float* __restrict__ E,       // [8][512][512] fp32
    float* __restrict__ u)       // [8][512]
{
  const int bid = blockIdx.x;
  const int tid = threadIdx.x;

  if (bid == NCH * 128) {        // chunk perm, one wave
    if (tid < 64) {
      float e = __expf(chunk_logits[tid] * TEMP_INV);
      float v = 1.0f, uu = 0.0f;
      #pragma unroll
      for (int it = 0; it < 5; ++it) {
        float t = e * v;
        t += __shfl_xor(t, 1); t += __shfl_xor(t, 2); t += __shfl_xor(t, 4);
        uu = 1.0f / t;
        float t2 = e * uu;
        t2 += __shfl_xor(t2, 8); t2 += __shfl_xor(t2, 16); t2 += __shfl_xor(t2, 32);
        v = 1.0f / t2;
      }
      cp[tid] = e * uu * v;
    }
    return;
  }

  const int c = bid >> 7;                 // 128 blocks per chunk
  const int w = tid >> 6, l = tid & 63;
  const int row = ((bid & 127) << 2) + w; // one wave per row
  const float* Lr = intra_logits + ((size_t)c * CS + row) * CS;
  float* Er = E + ((size_t)c * CS + row) * CS;

  float s = 0.0f;
  #pragma unroll
  for (int rd = 0; rd < 2; ++rd) {
    const int j = rd * 256 + l * 4;
    float4 t = *(const float4*)(Lr + j);
    float4 e;
    e.x = __expf(t.x * TEMP_INV); e.y = __expf(t.y * TEMP_INV);
    e.z = __expf(t.z * TEMP_INV); e.w = __expf(t.w * TEMP_INV);
    *(float4*)(Er + j) = e;
    s += e.x + e.y + e.z + e.w;
  }
  s += __shfl_xor(s, 1);  s += __shfl_xor(s, 2);  s += __shfl_xor(s, 4);
  s += __shfl_xor(s, 8);  s += __shfl_xor(s, 16); s += __shfl_xor(s, 32);
  if (l == 0) u[c * CS + row] = 1.0f / s;
}

// ---------------------------------------------------------------------------
// C1: column-pass partials. Block = (chunk, k-slab of 32, j-tile of 256).
// partial[c][slab][j] = sum_{k in slab} E[k,j] * u[k]
// ---------------------------------------------------------------------------
__global__ __launch_bounds__(256) void c1_kernel(
    const float* __restrict__ E,
    const float* __restrict__ u,
    float* __restrict__ partial)   // [8][NSLAB][512]
{
  const int bid = blockIdx.x;      // 8*16*2 = 256
  const int c  = bid >> 5;
  const int ks = (bid >> 1) & 15;
  const int jt = bid & 1;
  const int j  = jt * 256 + threadIdx.x;
  const float* Ec = E + (size_t)c * CS * CS;

  __shared__ float us[32];
  if (threadIdx.x < 32) us[threadIdx.x] = u[c * CS + ks * 32 + threadIdx.x];
  __syncthreads();

  float s = 0.0f;
  #pragma unroll 8
  for (int kk = 0; kk < 32; ++kk)
    s += Ec[(size_t)(ks * 32 + kk) * CS + j] * us[kk];
  partial[((size_t)c * NSLAB + ks) * CS + j] = s;
}

// ---------------------------------------------------------------------------
// R: combine partials -> v (LDS), then row pass u = 1/(E v). One wave/row.
// ---------------------------------------------------------------------------
__global__ __launch_bounds__(256) void r_kernel(
    const float* __restrict__ E,
    const float* __restrict__ partial,
    float* __restrict__ u)
{
  const int bid = blockIdx.x;      // 1024
  const int tid = threadIdx.x;
  const int c = bid >> 7;
  const float* pc = partial + (size_t)c * NSLAB * CS;

  __shared__ float vs[CS];
  #pragma unroll
  for (int rep = 0; rep < 2; ++rep) {
    const int j = rep * 256 + tid;
    float s = 0.0f;
    #pragma unroll
    for (int sl = 0; sl < NSLAB; ++sl) s += pc[sl * CS + j];
    vs[j] = 1.0f / s;
  }
  __syncthreads();

  const int w = tid >> 6, l = tid & 63;
  const int row = ((bid & 127) << 2) + w;
  const float* Er = E + ((size_t)c * CS + row) * CS;
  float s = 0.0f;
  #pragma unroll
  for (int rd = 0; rd < 2; ++rd) {
    const int j = rd * 256 + l * 4;
    float4 e = *(const float4*)(Er + j);
    float4 v = *(const float4*)(vs + j);
    s += e.x * v.x + e.y * v.y + e.z * v.z + e.w * v.w;
  }
  s += __shfl_xor(s, 1);  s += __shfl_xor(s, 2);  s += __shfl_xor(s, 4);
  s += __shfl_xor(s, 8);  s += __shfl_xor(s, 16); s += __shfl_xor(s, 32);
  if (l == 0) u[c * CS + row] = 1.0f / s;
}

// ---------------------------------------------------------------------------
// P: combine partials -> v, emit P = bf16(E * u * v). One wave per row.
// ---------------------------------------------------------------------------
__global__ __launch_bounds__(256) void p_kernel(
    const float* __restrict__ E,
    const float* __restrict__ partial,
    const float* __restrict__ u,
    u16* __restrict__ P)
{
  const int bid = blockIdx.x;      // 1024
  const int tid = threadIdx.x;
  const int c = bid >> 7;
  const float* pc = partial + (size_t)c * NSLAB * CS;

  __shared__ float vs[CS];
  #pragma unroll
  for (int rep = 0; rep < 2; ++rep) {
    const int j = rep * 256 + tid;
    float s = 0.0f;
    #pragma unroll
    for (int sl = 0; sl < NSLAB; ++sl) s += pc[sl * CS + j];
    vs[j] = 1.0f / s;
  }
  __syncthreads();

  const int w = tid >> 6, l = tid & 63;
  const int row = ((bid & 127) << 2) + w;
  const float uu = u[c * CS + row];
  const float* Er = E + ((size_t)c * CS + row) * CS;
  u16* Pr = P + ((size_t)c * CS + row) * CS;

  const int j0 = l * 8;
  float4 e0 = *(const float4*)(Er + j0);
  float4 e1 = *(const float4*)(Er + j0 + 4);
  float4 v0 = *(const float4*)(vs + j0);
  float4 v1 = *(const float4*)(vs + j0 + 4);
  u16x8 o;
  o[0] = f2bf(e0.x * uu * v0.x); o[1] = f2bf(e0.y * uu * v0.y);
  o[2] = f2bf(e0.z * uu * v0.z); o[3] = f2bf(e0.w * uu * v0.w);
  o[4] = f2bf(e1.x * uu * v1.x); o[5] = f2bf(e1.y * uu * v1.y);
  o[6] = f2bf(e1.z * uu * v1.z); o[7] = f2bf(e1.w * uu * v1.w);
  *(u16x8*)(Pr + j0) = o;
}

// ---------------------------------------------------------------------------
// stage1: ytil[b,i,d] = sum_jc cp[i,jc] * x[b,jc,d], fp32 -> bf16
// ---------------------------------------------------------------------------
__global__ __launch_bounds__(256) void stage1_kernel(
    const float* __restrict__ x,
    const float* __restrict__ cp,
    u16* __restrict__ y)
{
  __shared__ float cps[64];
  const int tid = threadIdx.x;
  if (tid < 64) cps[tid] = cp[tid];
  __syncthreads();

  const int g  = blockIdx.x * 256 + tid;   // over rows*128 float4 slots
  const int b  = g >> 7;
  const int d4 = g & 127;

  const float4* xr = (const float4*)x + (size_t)b * 1024 + d4;
  float4 xi[8];
  #pragma unroll
  for (int jc = 0; jc < 8; ++jc) xi[jc] = xr[(size_t)jc * 128];

  ushort4* yr = (ushort4*)y + (size_t)b * 1024 + d4;
  #pragma unroll
  for (int i = 0; i < 8; ++i) {
    float ax = 0.f, ay = 0.f, az = 0.f, aw = 0.f;
    #pragma unroll
    for (int jc = 0; jc < 8; ++jc) {
      const float wgt = cps[i * 8 + jc];
      ax += wgt * xi[jc].x; ay += wgt * xi[jc].y;
      az += wgt * xi[jc].z; aw += wgt * xi[jc].w;
    }
    ushort4 o;
    o.x = f2bf(ax); o.y = f2bf(ay); o.z = f2bf(az); o.w = f2bf(aw);
    yr[(size_t)i * 128] = o;
  }
}

// ---------------------------------------------------------------------------
// gemm: out[m, c, n] = sum_k ytil[m, c, k] * P_c[n, k].  m97 recipe.
// ---------------------------------------------------------------------------
#define BM 128
#define BN 128
#define BK 32

__global__ __launch_bounds__(256) void gemm_kernel(
    const u16* __restrict__ Y,   // [rows][4096] bf16 bits
    const u16* __restrict__ P,   // [8][512][512] bf16 bits
    float* __restrict__ out)     // [rows][4096] fp32
{
  __shared__ u16 As[BM * BK];
  __shared__ u16 Bs[BN * BK];

  const int tid = threadIdx.x;
  const int m0 = blockIdx.x * BM;
  const int n0 = blockIdx.y * BN;
  const int c  = blockIdx.z;

  const u16* Ab = Y + (size_t)m0 * DIM + (size_t)c * CS;
  const u16* Bb = P + (size_t)c * CS * CS + (size_t)n0 * CS;

  const int w = tid >> 6, l = tid & 63;
  const int wm = (w >> 1) * 64, wn = (w & 1) * 64;
  const int lrow = l & 15, lk = (l >> 4) * 8;
  const int colb = (tid & 3) * 8;

  f32x4 acc[4][4] = {};

  for (int k0 = 0; k0 < CS; k0 += BK) {
    #pragma unroll
    for (int rd = 0; rd < 2; ++rd) {
      const int idx = rd * 256 + tid;
      const int r = idx >> 2;
      const u16* g = Ab + (size_t)r * DIM + k0 + colb;
      u16* lds = As + ((idx >> 6) << 6) * 8;
      __builtin_amdgcn_global_load_lds((gas_ptr)g, (las_ptr)lds, 16, 0, 0);
    }
    #pragma unroll
    for (int rd = 0; rd < 2; ++rd) {
      const int idx = rd * 256 + tid;
      const int r = idx >> 2;
      const u16* g = Bb + (size_t)r * CS + k0 + colb;
      u16* lds = Bs + ((idx >> 6) << 6) * 8;
      __builtin_amdgcn_global_load_lds((gas_ptr)g, (las_ptr)lds, 16, 0, 0);
    }
    __syncthreads();

    bf16x8 af[4], bfr[4];
    #pragma unroll
    for (int mi = 0; mi < 4; ++mi)
      af[mi] = *(const bf16x8*)&As[(wm + mi * 16 + lrow) * BK + lk];
    #pragma unroll
    for (int ni = 0; ni < 4; ++ni)
      bfr[ni] = *(const bf16x8*)&Bs[(wn + ni * 16 + lrow) * BK + lk];

    #pragma unroll
    for (int mi = 0; mi < 4; ++mi)
      #pragma unroll
      for (int ni = 0; ni < 4; ++ni)
        acc[mi][ni] = __builtin_amdgcn_mfma_f32_16x16x32_bf16(
            af[mi], bfr[ni], acc[mi][ni], 0, 0, 0);
    __syncthreads();
  }

  const int ccol = l & 15, rquad = (l >> 4) * 4;
  #pragma unroll
  for (int mi = 0; mi < 4; ++mi) {
    #pragma unroll
    for (int ni = 0; ni < 4; ++ni) {
      #pragma unroll
      for (int r = 0; r < 4; ++r) {
        const int mm = m0 + wm + mi * 16 + rquad + r;
        const int nn = n0 + wn + ni * 16 + ccol;
        out[(size_t)mm * DIM + (size_t)c * CS + nn] = acc[mi][ni][r];
      }
    }
  }
}

// ---------------------------------------------------------------------------
// ws layout (Y overlaps dead E):
//   [0,1K)      cp
//   [1K,17K)    u        (8*512 f32)
//   [32K,288K)  partial  (8*16*512 f32)
//   [512K,4.5M) P bf16
//   [8M,16M)    E fp32   (dead after p_kernel)
//   [8M,136M)   Y bf16   (written by stage1, after E is dead)
// ---------------------------------------------------------------------------
extern "C" void kernel_launch(void* const* d_in, const int* in_sizes, int n_in,
                              void* d_out, int out_size, void* d_ws, size_t ws_size,
                              hipStream_t stream) {
  const float* x  = (const float*)d_in[0];
  const float* cl = (const float*)d_in[1];
  const float* il = (const float*)d_in[2];
  float* out = (float*)d_out;

  char* ws = (char*)d_ws;
  float* cp      = (float*)ws;
  float* u       = (float*)(ws + 1024);
  float* partial = (float*)(ws + 32 * 1024);
  u16*   P       = (u16*)(ws + 512 * 1024);
  float* E       = (float*)(ws + (size_t)8 * 1024 * 1024);
  u16*   Y       = (u16*)(ws + (size_t)8 * 1024 * 1024);

  const int rows = in_sizes[0] / DIM;   // 16384

  re_kernel<<<dim3(NCH * 128 + 1), dim3(256), 0, stream>>>(cl, il, cp, E, u);
  for (int it = 0; it < 4; ++it) {
    c1_kernel<<<dim3(256), dim3(256), 0, stream>>>(E, u, partial);
    r_kernel<<<dim3(1024), dim3(256), 0, stream>>>(E, partial, u);
  }
  c1_kernel<<<dim3(256), dim3(256), 0, stream>>>(E, u, partial);
  p_kernel<<<dim3(1024), dim3(256), 0, stream>>>(E, partial, u, P);

  stage1_kernel<<<dim3(rows / 2), dim3(256), 0, stream>>>(x, cp, Y);
  gemm_kernel<<<dim3(rows / BM, CS / BN, NCH), dim3(256), 0, stream>>>(Y, P, out);
}